// Round 6
// baseline (4442.305 us; speedup 1.0000x reference)
//
#include <hip/hip_runtime.h>
#include <math.h>

typedef unsigned short u16;
typedef unsigned int u32;
typedef __attribute__((ext_vector_type(2))) _Float16 h2;

#define kT 32
#define OUT_STATES 1048576   // T*B*D
#define OUT_M      1179648   // + 4*B*D

union H2U { u32 u; h2 h; };

__device__ __forceinline__ float dot2u(u32 w, u32 x, float acc){
  H2U a; a.u = w; H2U b; b.u = x;
#if __has_builtin(__builtin_amdgcn_fdot2)
  return __builtin_amdgcn_fdot2(a.h, b.h, acc, false);
#else
  acc += (float)a.h.x * (float)b.h.x;
  acc += (float)a.h.y * (float)b.h.y;
  return acc;
#endif
}
__device__ __forceinline__ u32 packf16(float x, float y){
  H2U v; v.h.x = (_Float16)x; v.h.y = (_Float16)y; return v.u;
}
__device__ __forceinline__ float red32sum(float v){
  #pragma unroll
  for (int m = 1; m <= 16; m <<= 1) v += __shfl_xor(v, m, 64);
  return v;
}
__device__ __forceinline__ float red32max(float v){
  #pragma unroll
  for (int m = 1; m <= 16; m <<= 1) v = fmaxf(v, __shfl_xor(v, m, 64));
  return v;
}

// ---- group barrier: 16 blocks/group, flag-per-block, monotone seq -----------
__device__ __forceinline__ void gbar(int* flags, int g, int c, int seq, int tid){
  __syncthreads();
  __threadfence();
  if (tid == 0)
    __hip_atomic_store(&flags[g*64 + c], seq, __ATOMIC_RELEASE,
                       __HIP_MEMORY_SCOPE_AGENT);
  if (tid < 16){
    while (__hip_atomic_load(&flags[g*64 + tid], __ATOMIC_ACQUIRE,
                             __HIP_MEMORY_SCOPE_AGENT) < seq)
      __builtin_amdgcn_s_sleep(2);
  }
  __threadfence();
  __syncthreads();
}

// ---------------- ws offsets (bytes) -----------------------------------------
// NOTE r6 fix: cmaxb/cSb are f32[2048] = 8 KB EACH (r5 allotted 4 KB -> the
// aliasing caused the inter-group race that failed graph-replay revalidation).
#define WS_WP1    0          // u32[262144]  1 MB
#define WS_WP2    1048576    // u32[262144]  1 MB
#define WS_WP3    2097152    // u32[65536]   256 KB
#define WS_BA     2359296    // f32[1024]
#define WS_BE     2363392    // f32[1024]
#define WS_BC     2367488    // f32[256]
#define WS_MASKP  2368512    // u32[4096]
#define WS_FLAGS1 2384896    // int[1024]
#define WS_FLAGS2 2388992    // int[1024]
#define WS_HRALL  2393088    // f32[32*128*256] 4 MB
#define WS_HWBUF  6587392    // f32[32768]
#define WS_COMPB  6718464    // f32[32768]
#define WS_SLOG   6849536    // f32[131072] 512 KB
#define WS_CMAX   7373824    // f32[2048]  8 KB
#define WS_CS     7382016    // f32[2048]  8 KB
#define WS_MACC   7390208    // f32[524288] 2 MB   (end 9487360)

// ---- prep: weight repack (f16, block/thread/reg layout), biases, mask, flags -
__global__ __launch_bounds__(1024) void k_prep(
        const float* __restrict__ Wih_r, const float* __restrict__ Whh_r,
        const float* __restrict__ bih_r, const float* __restrict__ bhh_r,
        const float* __restrict__ Wc,    const float* __restrict__ bc,
        const float* __restrict__ Wih_w, const float* __restrict__ Whh_w,
        const float* __restrict__ bih_w, const float* __restrict__ bhh_w,
        const unsigned char* __restrict__ maskraw, char* __restrict__ ws){
  u32* Wp1 = (u32*)(ws + WS_WP1);
  u32* Wp2 = (u32*)(ws + WS_WP2);
  u32* Wp3 = (u32*)(ws + WS_WP3);
  float* bA = (float*)(ws + WS_BA);
  float* bE = (float*)(ws + WS_BE);
  float* bcf = (float*)(ws + WS_BC);
  u32* maskp = (u32*)(ws + WS_MASKP);
  int* f1 = (int*)(ws + WS_FLAGS1);
  int* f2 = (int*)(ws + WS_FLAGS2);
  int idx = blockIdx.x * 1024 + threadIdx.x;
  if (idx < 524288){
    int i = idx & 262143;
    const float* Wi = (idx < 262144) ? Wih_r : Wih_w;
    const float* Wh = (idx < 262144) ? Whh_r : Whh_w;
    int t = i & 255, v = (i >> 8) & 15, j = (i >> 12) & 3, c = i >> 14;
    int lc = (t & 15) * 4 + j;
    int gc = (lc >> 4) * 256 + c * 16 + (lc & 15);
    int k = ((t >> 4) * 16 + v) * 2;
    float v0 = (k < 256) ? Wi[gc*256 + k]     : Wh[gc*256 + k - 256];
    float v1 = (k < 256) ? Wi[gc*256 + k + 1] : Wh[gc*256 + k + 1 - 256];
    ((idx < 262144) ? Wp1 : Wp2)[i] = packf16(v0, v1);
  } else if (idx < 589824){
    int i = idx - 524288;
    int t = i & 255, vv = (i >> 8) & 15, c = i >> 12;
    int gcol = c * 16 + (t & 15);
    int k = ((t >> 4) * 16 + vv) * 2;
    Wp3[i] = packf16(Wc[gcol*512 + k], Wc[gcol*512 + k + 1]);
  } else if (idx < 590848){
    int i = idx - 589824; bA[i] = bih_r[i] + bhh_r[i];
  } else if (idx < 591872){
    int i = idx - 590848; bE[i] = bih_w[i] + bhh_w[i];
  } else if (idx < 592128){
    int i = idx - 591872; bcf[i] = bc[i];
  } else if (idx < 596224){
    int i = idx - 592128;      // b*32 + la
    int b = i >> 5, la = i & 31;
    // mask dtype sniff (int32 / u8 / bf16 / fp32)
    bool sawBig = false, sawOdd = false, saw3F1 = false;
    for (int q = 0; q < 512; q++){
      unsigned char cch = maskraw[q];
      if (cch > 1u) sawBig = true;
      if ((q & 3) != 0 && cch != 0) sawOdd = true;
      if ((q & 3) == 1 && cch == 0x3F) saw3F1 = true;
    }
    int mode = (!sawBig) ? (sawOdd ? 1 : 0) : (saw3F1 ? 2 : 3);
    u32 bits = 0;
    for (int j = 0; j < 32; j++){
      int l = b * 1024 + la * 32 + j;
      unsigned char mv;
      if      (mode == 0) mv = (((const int*)maskraw)[l] != 0);
      else if (mode == 1) mv = (maskraw[l] != 0);
      else if (mode == 2) mv = ((maskraw[2*l] | maskraw[2*l+1]) != 0);
      else                mv = (((const unsigned int*)maskraw)[l] != 0);
      if (mv) bits |= (1u << j);
    }
    maskp[i] = bits;
  } else if (idx < 598272){
    int i = idx - 596224;
    if (i < 1024) f1[i] = 0; else f2[i - 1024] = 0;
  }
}

// ---- phase1: read-LSTM recurrence, all T steps -------------------------------
// grid 256 = 16 b-groups x 16 col-chunks; 256 thr; weights in VGPRs for all t.
__global__ __launch_bounds__(256, 1) void k_p1(
        const float* __restrict__ emb, const float* __restrict__ hr0,
        const float* __restrict__ cr0, char* __restrict__ ws,
        float* __restrict__ out){
  const u32* Wp1 = (const u32*)(ws + WS_WP1);
  const float* bA = (const float*)(ws + WS_BA);
  float* hrall = (float*)(ws + WS_HRALL);
  int* flags = (int*)(ws + WS_FLAGS1);
  int g = blockIdx.x >> 4, c = blockIdx.x & 15;
  int tid = threadIdx.x, lane = tid & 63, w = tid >> 6;
  int ks = tid >> 4;
  u32 wreg[4][16];
  #pragma unroll
  for (int j = 0; j < 4; j++)
    #pragma unroll
    for (int v = 0; v < 16; v++)
      wreg[j][v] = Wp1[((c*4 + j)*16 + v)*256 + tid];
  int pb = tid >> 4, pd = tid & 15;
  float bias4[4] = {0,0,0,0}, crreg = 0.f;
  if (tid < 128){
    #pragma unroll
    for (int q = 0; q < 4; q++) bias4[q] = bA[q*256 + c*16 + pd];
    crreg = cr0[(g*8 + pb)*256 + c*16 + pd];
  }
  __shared__ u32 xs[2048];
  __shared__ float gpart[4][16][4][8];
  for (int t = 0; t < kT; t++){
    const float* hrsrc = (t == 0) ? hr0 : (hrall + (size_t)(t-1)*32768);
    #pragma unroll
    for (int i = 0; i < 8; i++){
      int u = tid + 256*i, b = u >> 8, kk = u & 255;
      float2 pr;
      if (kk < 128) pr = *(const float2*)(emb + (size_t)t*32768 + (g*8+b)*256 + 2*kk);
      else          pr = *(const float2*)(hrsrc + (g*8+b)*256 + 2*(kk-128));
      xs[b*256 + kk] = packf16(pr.x, pr.y);
    }
    __syncthreads();
    float acc[4][8];
    #pragma unroll
    for (int j = 0; j < 4; j++)
      #pragma unroll
      for (int b = 0; b < 8; b++) acc[j][b] = 0.f;
    for (int b = 0; b < 8; b++){
      const uint4* xp = (const uint4*)&xs[b*256 + ks*16];
      uint4 x0 = xp[0], x1 = xp[1], x2 = xp[2], x3 = xp[3];
      #pragma unroll
      for (int j = 0; j < 4; j++){
        float a = acc[j][b];
        a = dot2u(wreg[j][0],  x0.x, a); a = dot2u(wreg[j][1],  x0.y, a);
        a = dot2u(wreg[j][2],  x0.z, a); a = dot2u(wreg[j][3],  x0.w, a);
        a = dot2u(wreg[j][4],  x1.x, a); a = dot2u(wreg[j][5],  x1.y, a);
        a = dot2u(wreg[j][6],  x1.z, a); a = dot2u(wreg[j][7],  x1.w, a);
        a = dot2u(wreg[j][8],  x2.x, a); a = dot2u(wreg[j][9],  x2.y, a);
        a = dot2u(wreg[j][10], x2.z, a); a = dot2u(wreg[j][11], x2.w, a);
        a = dot2u(wreg[j][12], x3.x, a); a = dot2u(wreg[j][13], x3.y, a);
        a = dot2u(wreg[j][14], x3.z, a); a = dot2u(wreg[j][15], x3.w, a);
        acc[j][b] = a;
      }
    }
    #pragma unroll
    for (int j = 0; j < 4; j++)
      #pragma unroll
      for (int b = 0; b < 8; b++){
        float v = acc[j][b];
        v += __shfl_xor(v, 16, 64);
        v += __shfl_xor(v, 32, 64);
        acc[j][b] = v;
      }
    if (lane < 16){
      #pragma unroll
      for (int j = 0; j < 4; j++)
        #pragma unroll
        for (int b = 0; b < 8; b++) gpart[w][lane][j][b] = acc[j][b];
    }
    __syncthreads();
    if (tid < 128){
      float gate[4];
      #pragma unroll
      for (int q = 0; q < 4; q++){
        int lc = q*16 + pd;
        float s = bias4[q];
        #pragma unroll
        for (int ww = 0; ww < 4; ww++) s += gpart[ww][lc>>2][lc&3][pb];
        gate[q] = s;
      }
      float i_ = 1.f/(1.f + expf(-gate[0]));
      float f_ = 1.f/(1.f + expf(-gate[1]));
      float g_ = tanhf(gate[2]);
      float o_ = 1.f/(1.f + expf(-gate[3]));
      float c2 = f_*crreg + i_*g_;
      crreg = c2;
      float h = o_*tanhf(c2);
      hrall[(size_t)t*32768 + (g*8+pb)*256 + c*16 + pd] = h;
      if (t == kT-1){
        out[OUT_STATES +         (g*8+pb)*256 + c*16 + pd] = h;
        out[OUT_STATES + 32768 + (g*8+pb)*256 + c*16 + pd] = c2;
      }
    }
    if (t < kT-1) gbar(flags, g, c, t+1, tid);
  }
}

// ---- phase2: attention + comp + write-LSTM + M epilogue ----------------------
__global__ __launch_bounds__(256, 1) void k_p2(
        const float* __restrict__ M0, const float* __restrict__ hw0,
        const float* __restrict__ cw0, char* __restrict__ ws,
        float* __restrict__ out){
  const u32* Wp2 = (const u32*)(ws + WS_WP2);
  const u32* Wp3 = (const u32*)(ws + WS_WP3);
  const float* bE = (const float*)(ws + WS_BE);
  const float* bcf = (const float*)(ws + WS_BC);
  const u32* maskp = (const u32*)(ws + WS_MASKP);
  float* hrall = (float*)(ws + WS_HRALL);
  float* hwbuf = (float*)(ws + WS_HWBUF);
  float* compb = (float*)(ws + WS_COMPB);
  float* slog  = (float*)(ws + WS_SLOG);
  float* cmaxb = (float*)(ws + WS_CMAX);
  float* cSb   = (float*)(ws + WS_CS);
  float* maccb = (float*)(ws + WS_MACC);
  int* flags = (int*)(ws + WS_FLAGS2);
  int g = blockIdx.x >> 4, c = blockIdx.x & 15;
  int tid = threadIdx.x, lane = tid & 63, w = tid >> 6;
  int ks = tid >> 4;
  u32 wereg[4][16];
  #pragma unroll
  for (int j = 0; j < 4; j++)
    #pragma unroll
    for (int v = 0; v < 16; v++)
      wereg[j][v] = Wp2[((c*4 + j)*16 + v)*256 + tid];
  u32 wcreg[16];
  #pragma unroll
  for (int v = 0; v < 16; v++) wcreg[v] = Wp3[(c*16 + v)*256 + tid];
  int pb = tid >> 4, pd = tid & 15;
  float biasE4[4] = {0,0,0,0}, cwreg = 0.f, bcc = 0.f;
  if (tid < 128){
    #pragma unroll
    for (int q = 0; q < 4; q++) biasE4[q] = bE[q*256 + c*16 + pd];
    cwreg = cw0[(g*8 + pb)*256 + c*16 + pd];
    bcc = bcf[c*16 + (tid >> 3)];
  }
  int zb = tid >> 5, la = tid & 31;
  u32 maskbits = maskp[(g*8 + zb)*32 + la];
  float zp[32];
  #pragma unroll
  for (int j = 0; j < 32; j++) zp[j] = 0.f;
  __shared__ float hrl[2048], hwl[2048];
  __shared__ u32 xs[2048];
  __shared__ float gpart[4][16][4][8];
  __shared__ float cpart[4][16][8];
  __shared__ float sbuf[8][64];
  __shared__ float zl[8][64];
  #pragma unroll
  for (int i = 0; i < 8; i++){
    int u = tid + 256*i;
    hwl[u] = hw0[(g*8 + (u>>8))*256 + (u & 255)];
  }
  int bseq = 0;
  for (int t = 0; t < kT; t++){
    #pragma unroll
    for (int i = 0; i < 8; i++){
      int u = tid + 256*i;
      hrl[u] = hrall[(size_t)t*32768 + (g*8 + (u>>8))*256 + (u & 255)];
    }
    __syncthreads();
    float mval[8];
    if (t == 0){
      // pass1: logits for rows (b in group, l in chunk c)
      int rw = tid >> 2, seg = tid & 3;
      int pb1 = rw >> 3, lof = rw & 7;
      for (int it = 0; it < 8; it++){
        int l = c*64 + it*8 + lof;
        const float4* row = (const float4*)(M0 +
            ((size_t)(g*8 + pb1)*1024 + l)*256 + seg*64);
        float part = 0.f;
        #pragma unroll
        for (int ii = 0; ii < 16; ii++){
          float4 mv = row[ii];
          float4 hv = *(const float4*)&hrl[pb1*256 + seg*64 + ii*4];
          part += mv.x*hv.x + mv.y*hv.y + mv.z*hv.z + mv.w*hv.w;
        }
        part += __shfl_xor(part, 1, 64);
        part += __shfl_xor(part, 2, 64);
        if (seg == 0){
          u32 mw = maskp[(g*8 + pb1)*32 + (l >> 5)];
          float s = ((mw >> (l & 31)) & 1u) ? -INFINITY : part;
          sbuf[pb1][it*8 + lof] = s;
          slog[(g*8 + pb1)*1024 + l] = s;
        }
      }
      __syncthreads();
      float cm = fmaxf(sbuf[zb][2*la], sbuf[zb][2*la + 1]);
      cm = red32max(cm);
      if (la == 0) cmaxb[(g*16 + c)*8 + zb] = cm;
      gbar(flags, g, c, ++bseq, tid);
      float gm = (la < 16) ? cmaxb[(g*16 + la)*8 + zb] : -INFINITY;
      gm = red32max(gm);
      // pass2: exp-weighted accumulation over chunk
      float macc[8];
      #pragma unroll
      for (int i = 0; i < 8; i++) macc[i] = 0.f;
      float Sl = 0.f;
      for (int ll = 0; ll < 64; ll++){
        float p = expf(sbuf[zb][ll] - gm);
        Sl += p;
        const float4* row = (const float4*)(M0 +
            ((size_t)(g*8 + zb)*1024 + c*64 + ll)*256 + la*8);
        float4 r0 = row[0], r1 = row[1];
        macc[0] += p*r0.x; macc[1] += p*r0.y; macc[2] += p*r0.z; macc[3] += p*r0.w;
        macc[4] += p*r1.x; macc[5] += p*r1.y; macc[6] += p*r1.z; macc[7] += p*r1.w;
      }
      float* mb = &maccb[(size_t)((g*16 + c)*8 + zb)*256 + la*8];
      *(float4*)mb       = make_float4(macc[0], macc[1], macc[2], macc[3]);
      *(float4*)(mb + 4) = make_float4(macc[4], macc[5], macc[6], macc[7]);
      if (la == 0) cSb[(g*16 + c)*8 + zb] = Sl;
      gbar(flags, g, c, ++bseq, tid);
      float Sg = (la < 16) ? cSb[(g*16 + la)*8 + zb] : 0.f;
      Sg = red32sum(Sg);
      float msum[8];
      #pragma unroll
      for (int i = 0; i < 8; i++) msum[i] = 0.f;
      for (int cc = 0; cc < 16; cc++){
        const float* mr = &maccb[(size_t)((g*16 + cc)*8 + zb)*256 + la*8];
        float4 a0 = *(const float4*)mr, a1 = *(const float4*)(mr + 4);
        msum[0] += a0.x; msum[1] += a0.y; msum[2] += a0.z; msum[3] += a0.w;
        msum[4] += a1.x; msum[5] += a1.y; msum[6] += a1.z; msum[7] += a1.w;
      }
      #pragma unroll
      for (int i = 0; i < 8; i++) mval[i] = msum[i] / Sg;
      const float* sr = &slog[(g*8 + zb)*1024 + la*32];
      #pragma unroll
      for (int jq = 0; jq < 8; jq++){
        float4 sv = *(const float4*)(sr + jq*4);
        zp[jq*4 + 0] = expf(sv.x - gm) / Sg;
        zp[jq*4 + 1] = expf(sv.y - gm) / Sg;
        zp[jq*4 + 2] = expf(sv.z - gm) / Sg;
        zp[jq*4 + 3] = expf(sv.w - gm) / Sg;
      }
    } else {
      // factored memory: M = (1-zp) + hw_prev (x) zp
      float s1p = 0.f, s2p = 0.f;
      #pragma unroll
      for (int i = 0; i < 8; i++){
        float hv = hrl[zb*256 + la*8 + i];
        s1p += hv;
        s2p += hv * hwl[zb*256 + la*8 + i];
      }
      float S1 = red32sum(s1p), S2 = red32sum(s2p);
      float sv[32], lmax = -INFINITY;
      #pragma unroll
      for (int j = 0; j < 32; j++){
        float zo = zp[j];
        float s = ((maskbits >> j) & 1u) ? -INFINITY : (1.f - zo)*S1 + zo*S2;
        sv[j] = s;
        lmax = fmaxf(lmax, s);
      }
      float gm = red32max(lmax);
      float ls = 0.f;
      #pragma unroll
      for (int j = 0; j < 32; j++){ sv[j] = expf(sv[j] - gm); ls += sv[j]; }
      float Ssum = red32sum(ls);
      float Ap = 0.f, Cp = 0.f;
      #pragma unroll
      for (int j = 0; j < 32; j++){
        float zn = sv[j] / Ssum;
        Ap += zn * (1.f - zp[j]);
        Cp += zn * zp[j];
        zp[j] = zn;
      }
      float Ab = red32sum(Ap), Cb = red32sum(Cp);
      #pragma unroll
      for (int i = 0; i < 8; i++) mval[i] = Ab + hwl[zb*256 + la*8 + i]*Cb;
    }
    // pack xc = [hr | m] as f16 pairs
    #pragma unroll
    for (int i = 0; i < 4; i++){
      int kk = la*4 + i;
      xs[zb*256 + kk] = packf16(hrl[zb*256 + 2*kk], hrl[zb*256 + 2*kk + 1]);
      xs[zb*256 + 128 + kk] = packf16(mval[2*i], mval[2*i + 1]);
    }
    __syncthreads();
    // comp logits chunk (16 cols)
    {
      float accC[8];
      #pragma unroll
      for (int b = 0; b < 8; b++) accC[b] = 0.f;
      for (int b = 0; b < 8; b++){
        const uint4* xp = (const uint4*)&xs[b*256 + ks*16];
        uint4 x0 = xp[0], x1 = xp[1], x2 = xp[2], x3 = xp[3];
        float a = 0.f;
        a = dot2u(wcreg[0],  x0.x, a); a = dot2u(wcreg[1],  x0.y, a);
        a = dot2u(wcreg[2],  x0.z, a); a = dot2u(wcreg[3],  x0.w, a);
        a = dot2u(wcreg[4],  x1.x, a); a = dot2u(wcreg[5],  x1.y, a);
        a = dot2u(wcreg[6],  x1.z, a); a = dot2u(wcreg[7],  x1.w, a);
        a = dot2u(wcreg[8],  x2.x, a); a = dot2u(wcreg[9],  x2.y, a);
        a = dot2u(wcreg[10], x2.z, a); a = dot2u(wcreg[11], x2.w, a);
        a = dot2u(wcreg[12], x3.x, a); a = dot2u(wcreg[13], x3.y, a);
        a = dot2u(wcreg[14], x3.z, a); a = dot2u(wcreg[15], x3.w, a);
        accC[b] = a;
      }
      #pragma unroll
      for (int b = 0; b < 8; b++){
        float v = accC[b];
        v += __shfl_xor(v, 16, 64);
        v += __shfl_xor(v, 32, 64);
        accC[b] = v;
      }
      if (lane < 16){
        #pragma unroll
        for (int b = 0; b < 8; b++) cpart[w][lane][b] = accC[b];
      }
      __syncthreads();
      if (tid < 128){
        int ccol = tid >> 3, cb = tid & 7;
        float e = bcc;
        #pragma unroll
        for (int ww = 0; ww < 4; ww++) e += cpart[ww][ccol][cb];
        compb[(g*8 + cb)*256 + c*16 + ccol] = e;
      }
    }
    gbar(flags, g, c, ++bseq, tid);
    // softmax(comp) redundantly per block; pack xe = [comp | hw]
    {
      const float* ce = &compb[(g*8 + zb)*256 + la*8];
      float4 e0 = *(const float4*)ce, e1 = *(const float4*)(ce + 4);
      float ev[8] = {e0.x, e0.y, e0.z, e0.w, e1.x, e1.y, e1.z, e1.w};
      float lm = -INFINITY;
      #pragma unroll
      for (int i = 0; i < 8; i++) lm = fmaxf(lm, ev[i]);
      float cm = red32max(lm);
      float lsum = 0.f;
      #pragma unroll
      for (int i = 0; i < 8; i++){ ev[i] = expf(ev[i] - cm); lsum += ev[i]; }
      float cs = red32sum(lsum);
      #pragma unroll
      for (int i = 0; i < 4; i++){
        int kk = la*4 + i;
        xs[zb*256 + kk] = packf16(ev[2*i]/cs, ev[2*i + 1]/cs);
        xs[zb*256 + 128 + kk] = packf16(hwl[zb*256 + 2*kk], hwl[zb*256 + 2*kk + 1]);
      }
    }
    __syncthreads();
    // write-LSTM gemv chunk
    float acc[4][8];
    #pragma unroll
    for (int j = 0; j < 4; j++)
      #pragma unroll
      for (int b = 0; b < 8; b++) acc[j][b] = 0.f;
    for (int b = 0; b < 8; b++){
      const uint4* xp = (const uint4*)&xs[b*256 + ks*16];
      uint4 x0 = xp[0], x1 = xp[1], x2 = xp[2], x3 = xp[3];
      #pragma unroll
      for (int j = 0; j < 4; j++){
        float a = acc[j][b];
        a = dot2u(wereg[j][0],  x0.x, a); a = dot2u(wereg[j][1],  x0.y, a);
        a = dot2u(wereg[j][2],  x0.z, a); a = dot2u(wereg[j][3],  x0.w, a);
        a = dot2u(wereg[j][4],  x1.x, a); a = dot2u(wereg[j][5],  x1.y, a);
        a = dot2u(wereg[j][6],  x1.z, a); a = dot2u(wereg[j][7],  x1.w, a);
        a = dot2u(wereg[j][8],  x2.x, a); a = dot2u(wereg[j][9],  x2.y, a);
        a = dot2u(wereg[j][10], x2.z, a); a = dot2u(wereg[j][11], x2.w, a);
        a = dot2u(wereg[j][12], x3.x, a); a = dot2u(wereg[j][13], x3.y, a);
        a = dot2u(wereg[j][14], x3.z, a); a = dot2u(wereg[j][15], x3.w, a);
        acc[j][b] = a;
      }
    }
    #pragma unroll
    for (int j = 0; j < 4; j++)
      #pragma unroll
      for (int b = 0; b < 8; b++){
        float v = acc[j][b];
        v += __shfl_xor(v, 16, 64);
        v += __shfl_xor(v, 32, 64);
        acc[j][b] = v;
      }
    if (lane < 16){
      #pragma unroll
      for (int j = 0; j < 4; j++)
        #pragma unroll
        for (int b = 0; b < 8; b++) gpart[w][lane][j][b] = acc[j][b];
    }
    __syncthreads();
    if (tid < 128){
      float gate[4];
      #pragma unroll
      for (int q = 0; q < 4; q++){
        int lc = q*16 + pd;
        float s = biasE4[q];
        #pragma unroll
        for (int ww = 0; ww < 4; ww++) s += gpart[ww][lc>>2][lc&3][pb];
        gate[q] = s;
      }
      float i_ = 1.f/(1.f + expf(-gate[0]));
      float f_ = 1.f/(1.f + expf(-gate[1]));
      float g_ = tanhf(gate[2]);
      float o_ = 1.f/(1.f + expf(-gate[3]));
      float c2 = f_*cwreg + i_*g_;
      cwreg = c2;
      float h = o_*tanhf(c2);
      out[(size_t)t*32768 + (g*8+pb)*256 + c*16 + pd] = h;
      hwbuf[(g*8+pb)*256 + c*16 + pd] = h;
    }
    gbar(flags, g, c, ++bseq, tid);
    #pragma unroll
    for (int i = 0; i < 8; i++){
      int u = tid + 256*i;
      hwl[u] = hwbuf[(g*8 + (u>>8))*256 + (u & 255)];
    }
    __syncthreads();
  }
  // final states
  if (tid < 128){
    out[OUT_STATES + 65536 + (g*8+pb)*256 + c*16 + pd] = hwl[pb*256 + c*16 + pd];
    out[OUT_STATES + 98304 + (g*8+pb)*256 + c*16 + pd] = cwreg;
  }
  // epilogue: M = (1-z) + hw (x) z for rows (b in group, l in chunk c)
  if ((la >> 1) == c){
    #pragma unroll
    for (int j = 0; j < 32; j++) zl[zb][(la & 1)*32 + j] = zp[j];
  }
  __syncthreads();
  float* Mout = out + OUT_M;
  for (int it = 0; it < 64; it++){
    int r = it*8 + (tid >> 5);
    int rb = r >> 6, ll = r & 63;
    float z = zl[rb][ll], omz = 1.f - z;
    int d0 = la*8;
    float4 v0, v1;
    v0.x = omz + hwl[rb*256 + d0    ]*z;  v0.y = omz + hwl[rb*256 + d0 + 1]*z;
    v0.z = omz + hwl[rb*256 + d0 + 2]*z;  v0.w = omz + hwl[rb*256 + d0 + 3]*z;
    v1.x = omz + hwl[rb*256 + d0 + 4]*z;  v1.y = omz + hwl[rb*256 + d0 + 5]*z;
    v1.z = omz + hwl[rb*256 + d0 + 6]*z;  v1.w = omz + hwl[rb*256 + d0 + 7]*z;
    float* dst = Mout + ((size_t)(g*8 + rb)*1024 + c*64 + ll)*256 + d0;
    *(float4*)dst = v0;
    *(float4*)(dst + 4) = v1;
  }
}

extern "C" void kernel_launch(void* const* d_in, const int* in_sizes, int n_in,
                              void* d_out, int out_size, void* d_ws, size_t ws_size,
                              hipStream_t stream){
  const float* emb   = (const float*)d_in[0];
  const float* hr0   = (const float*)d_in[1];
  const float* cr0   = (const float*)d_in[2];
  const float* hw0   = (const float*)d_in[3];
  const float* cw0   = (const float*)d_in[4];
  const float* M0    = (const float*)d_in[5];
  const unsigned char* maskraw = (const unsigned char*)d_in[6];
  const float* Wih_r = (const float*)d_in[7];
  const float* Whh_r = (const float*)d_in[8];
  const float* bih_r = (const float*)d_in[9];
  const float* bhh_r = (const float*)d_in[10];
  const float* Wc    = (const float*)d_in[11];
  const float* bc    = (const float*)d_in[12];
  const float* Wih_w = (const float*)d_in[13];
  const float* Whh_w = (const float*)d_in[14];
  const float* bih_w = (const float*)d_in[15];
  const float* bhh_w = (const float*)d_in[16];
  float* out = (float*)d_out;
  char* ws = (char*)d_ws;

  k_prep<<<dim3(585), dim3(1024), 0, stream>>>(
      Wih_r, Whh_r, bih_r, bhh_r, Wc, bc, Wih_w, Whh_w, bih_w, bhh_w,
      maskraw, ws);
  k_p1<<<dim3(256), dim3(256), 0, stream>>>(emb, hr0, cr0, ws, out);
  k_p2<<<dim3(256), dim3(256), 0, stream>>>(M0, hw0, cw0, ws, out);
}